// Round 8
// baseline (301.844 us; speedup 1.0000x reference)
//
#include <hip/hip_runtime.h>
#include <math.h>

// Shapes: B=8, N=256, NID=64, V=GH=128, PHI=256, RHO=128
#define NB 8
#define GRID 256

typedef __attribute__((address_space(1))) const void* gas1p;
typedef __attribute__((address_space(3))) void* las3p;
static __device__ __forceinline__ void gld16(const float* g, float* l) {
    __builtin_amdgcn_global_load_lds((gas1p)g, (las3p)l, 16, 0, 0);
}

struct Params {
    const float *A, *X, *hm;
    const float *e1w, *e1b, *e2w, *e2b;
    const float *rw0, *rr0, *rb0, *law0, *lab0, *lbw0, *lbb0;
    const float *rw1, *rr1, *rb1, *law1, *lab1, *lbw1, *lbb1;
    const float *ng, *nbta;
    const float *pw1, *pb1, *pw2, *pb2;
    const float *qw1, *qb1, *qw2, *qb2;
    float *H, *H2, *hsum, *asum, *outp;
    int *cnt;
};

__global__ __launch_bounds__(256) void k_init(float* pools, int* cnt) {
    int i = blockIdx.x * 256 + threadIdx.x;
    if (i < 4096) pools[i] = 0.f;
    if (blockIdx.x == 16 && threadIdx.x < 16) cnt[threadIdx.x] = 0;
}

__device__ __forceinline__ void gridbar(int* cnt, int id) {
    __syncthreads();
    if (threadIdx.x == 0) {
        __threadfence();
        __hip_atomic_fetch_add(&cnt[id], 1, __ATOMIC_RELAXED, __HIP_MEMORY_SCOPE_AGENT);
        while (__hip_atomic_load(&cnt[id], __ATOMIC_RELAXED,
                                 __HIP_MEMORY_SCOPE_AGENT) < GRID)
            __builtin_amdgcn_s_sleep(4);
        __threadfence();
    }
    __syncthreads();
}

// ---------------------------------------------------------------------------
__device__ void stage_gcn1(float* S, const float* Ab, const float* Hb,
        const float* Wrel, const float* Wroot, const float* bias,
        float* H2b, int j0, int t, int q, int u) {
    float* ldsM = S;            // 4096 [i*16 + rel*8 + r]
    float* ht   = S + 4096;     // dbuf 2*4096 (alias: part)
    float* part = S + 4096;
    float* pb   = S + 12288;    // 3072 [k*24 + {h8|m0_8|m1_8}]
    float* Wt   = S;            // phase B dbuf 2*6144
    float* cntp = S + 15360;    // 256
    float* cnt  = S + 15616;    // 16
    const float* W0 = Wrel;
    const float* W1 = Wrel + 16384;

    {
        float4 a0 = *(const float4*)(Ab + (size_t)t * 256 + j0);
        float4 a1 = *(const float4*)(Ab + (size_t)t * 256 + j0 + 4);
        *(float4*)&ldsM[t * 16] = make_float4(
            (a0.x < 0.f) ? 1.f : 0.f, (a0.y < 0.f) ? 1.f : 0.f,
            (a0.z < 0.f) ? 1.f : 0.f, (a0.w < 0.f) ? 1.f : 0.f);
        *(float4*)&ldsM[t * 16 + 4] = make_float4(
            (a1.x < 0.f) ? 1.f : 0.f, (a1.y < 0.f) ? 1.f : 0.f,
            (a1.z < 0.f) ? 1.f : 0.f, (a1.w < 0.f) ? 1.f : 0.f);
        *(float4*)&ldsM[t * 16 + 8] = make_float4(
            (a0.x > 0.f) ? 1.f : 0.f, (a0.y > 0.f) ? 1.f : 0.f,
            (a0.z > 0.f) ? 1.f : 0.f, (a0.w > 0.f) ? 1.f : 0.f);
        *(float4*)&ldsM[t * 16 + 12] = make_float4(
            (a1.x > 0.f) ? 1.f : 0.f, (a1.y > 0.f) ? 1.f : 0.f,
            (a1.z > 0.f) ? 1.f : 0.f, (a1.w > 0.f) ? 1.f : 0.f);
    }
    #pragma unroll
    for (int rnd = 0; rnd < 4; ++rnd) {
        int idx = rnd * 256 + t;
        gld16(Hb + idx * 4, &ht[idx * 4]);
    }
    __syncthreads();
    {
        int chunk = t >> 4, slot = t & 15;
        float c = 0.f;
        #pragma unroll
        for (int qq = 0; qq < 16; ++qq) c += ldsM[(chunk * 16 + qq) * 16 + slot];
        cntp[slot * 16 + chunk] = c;
    }
    float acc0[32], acc1[32];
    #pragma unroll
    for (int i = 0; i < 32; ++i) { acc0[i] = 0.f; acc1[i] = 0.f; }
    #pragma unroll 1
    for (int tl = 0; tl < 8; ++tl) {
        const int buf = tl & 1;
        if (tl < 7) {
            #pragma unroll
            for (int rnd = 0; rnd < 4; ++rnd) {
                int idx = rnd * 256 + t;
                gld16(Hb + (tl + 1) * 4096 + idx * 4, &ht[(buf ^ 1) * 4096 + idx * 4]);
            }
        }
        const float* hb = &ht[buf * 4096];
        #pragma unroll
        for (int ii = 0; ii < 4; ++ii) {
            int iL = u * 4 + ii;
            int i  = tl * 32 + iL;
            float4 h4 = *(const float4*)&hb[iL * 128 + q * 4];
            float hc[4] = {h4.x, h4.y, h4.z, h4.w};
            float4 m0a = *(const float4*)&ldsM[i * 16];
            float4 m0b = *(const float4*)&ldsM[i * 16 + 4];
            float4 m1a = *(const float4*)&ldsM[i * 16 + 8];
            float4 m1b = *(const float4*)&ldsM[i * 16 + 12];
            float mr0[8] = {m0a.x, m0a.y, m0a.z, m0a.w, m0b.x, m0b.y, m0b.z, m0b.w};
            float mr1[8] = {m1a.x, m1a.y, m1a.z, m1a.w, m1b.x, m1b.y, m1b.z, m1b.w};
            #pragma unroll
            for (int r = 0; r < 8; ++r)
                #pragma unroll
                for (int c = 0; c < 4; ++c) {
                    acc0[r * 4 + c] = fmaf(mr0[r], hc[c], acc0[r * 4 + c]);
                    acc1[r * 4 + c] = fmaf(mr1[r], hc[c], acc1[r * 4 + c]);
                }
        }
        __syncthreads();
    }
    if (t < 16) {
        float s = 0.f;
        #pragma unroll
        for (int c = 0; c < 16; ++c) s += cntp[t * 16 + c];
        cnt[t] = s;
    }
    #pragma unroll
    for (int e = 0; e < 4; ++e) {
        int idx = e * 256 + t;
        int r = idx >> 7, k = idx & 127;
        pb[k * 24 + r] = Hb[(size_t)(j0 + r) * 128 + k];
    }
    #pragma unroll
    for (int r = 0; r < 8; ++r)
        *(float4*)&part[u * 1024 + r * 128 + q * 4] =
            make_float4(acc0[r*4+0], acc0[r*4+1], acc0[r*4+2], acc0[r*4+3]);
    __syncthreads();
    #pragma unroll
    for (int e = 0; e < 4; ++e) {
        int idx = e * 256 + t;
        int r = idx >> 7, k = idx & 127;
        float s = 0.f;
        #pragma unroll
        for (int uu = 0; uu < 8; ++uu) s += part[uu * 1024 + r * 128 + k];
        pb[k * 24 + 8 + r] = s / fmaxf(cnt[r], 1.f);
    }
    __syncthreads();
    #pragma unroll
    for (int r = 0; r < 8; ++r)
        *(float4*)&part[u * 1024 + r * 128 + q * 4] =
            make_float4(acc1[r*4+0], acc1[r*4+1], acc1[r*4+2], acc1[r*4+3]);
    __syncthreads();
    #pragma unroll
    for (int e = 0; e < 4; ++e) {
        int idx = e * 256 + t;
        int r = idx >> 7, k = idx & 127;
        float s = 0.f;
        #pragma unroll
        for (int uu = 0; uu < 8; ++uu) s += part[uu * 1024 + r * 128 + k];
        pb[k * 24 + 16 + r] = s / fmaxf(cnt[8 + r], 1.f);
    }
    __syncthreads();
    #pragma unroll
    for (int rnd = 0; rnd < 6; ++rnd) {
        int idx = rnd * 256 + t;
        int mat = idx >> 9, rem = idx & 511;
        const float* Wm = (mat == 0) ? Wroot : ((mat == 1) ? W0 : W1);
        gld16(Wm + rem * 4, &Wt[mat * 2048 + rem * 4]);
    }
    __syncthreads();
    float bcc[32];
    #pragma unroll
    for (int i = 0; i < 32; ++i) bcc[i] = 0.f;
    #pragma unroll 1
    for (int kt = 0; kt < 8; ++kt) {
        const int buf = kt & 1;
        if (kt < 7) {
            #pragma unroll
            for (int rnd = 0; rnd < 6; ++rnd) {
                int idx = rnd * 256 + t;
                int mat = idx >> 9, rem = idx & 511;
                const float* Wm = (mat == 0) ? Wroot : ((mat == 1) ? W0 : W1);
                gld16(Wm + (kt + 1) * 2048 + rem * 4,
                      &Wt[(buf ^ 1) * 6144 + mat * 2048 + rem * 4]);
            }
        }
        const float* wt = &Wt[buf * 6144];
        #pragma unroll
        for (int kk = 0; kk < 2; ++kk) {
            int kl = u * 2 + kk;
            int k  = kt * 16 + kl;
            float4 wr4 = *(const float4*)&wt[kl * 128 + q * 4];
            float4 wa4 = *(const float4*)&wt[2048 + kl * 128 + q * 4];
            float4 wb4 = *(const float4*)&wt[4096 + kl * 128 + q * 4];
            float wrc[4] = {wr4.x, wr4.y, wr4.z, wr4.w};
            float wac[4] = {wa4.x, wa4.y, wa4.z, wa4.w};
            float wbc[4] = {wb4.x, wb4.y, wb4.z, wb4.w};
            const float* pk = &pb[k * 24];
            float4 hA = *(const float4*)pk,        hB = *(const float4*)(pk + 4);
            float4 qA = *(const float4*)(pk + 8),  qB = *(const float4*)(pk + 12);
            float4 rA = *(const float4*)(pk + 16), rB = *(const float4*)(pk + 20);
            float hr[8]  = {hA.x, hA.y, hA.z, hA.w, hB.x, hB.y, hB.z, hB.w};
            float m0r[8] = {qA.x, qA.y, qA.z, qA.w, qB.x, qB.y, qB.z, qB.w};
            float m1r[8] = {rA.x, rA.y, rA.z, rA.w, rB.x, rB.y, rB.z, rB.w};
            #pragma unroll
            for (int r = 0; r < 8; ++r)
                #pragma unroll
                for (int c = 0; c < 4; ++c) {
                    float v = bcc[r * 4 + c];
                    v = fmaf(hr[r], wrc[c], v);
                    v = fmaf(m0r[r], wac[c], v);
                    v = fmaf(m1r[r], wbc[c], v);
                    bcc[r * 4 + c] = v;
                }
        }
        __syncthreads();
    }
    float* bpart = S;
    #pragma unroll
    for (int r = 0; r < 8; ++r)
        *(float4*)&bpart[u * 1024 + r * 128 + q * 4] =
            make_float4(bcc[r*4+0], bcc[r*4+1], bcc[r*4+2], bcc[r*4+3]);
    __syncthreads();
    #pragma unroll
    for (int e = 0; e < 4; ++e) {
        int idx = e * 256 + t;
        int r = idx >> 7, f = idx & 127;
        float s = bias[f];
        #pragma unroll
        for (int uu = 0; uu < 8; ++uu) s += bpart[uu * 1024 + r * 128 + f];
        H2b[(size_t)(j0 + r) * 128 + f] = s;
    }
    __syncthreads();
}

// ---------------------------------------------------------------------------
__device__ void stage_gcn2(float* S, const float* Ab, const float* H2b,
        const float* g, const float* bta, const float* law, const float* lab,
        const float* lbw, const float* lbb, float* Hb, int i0, int t, int q, int u) {
    float* absA = S;            // 2048 [j*8 + r]
    float* ht   = S + 2048;     // dbuf 2*4096 (alias: part)
    float* part = S + 2048;
    float* xq   = S + 10240;    // 1024 [k*8+r]
    float* uq   = S + 11264;    // 1024
    float* Wt   = S + 12288;    // dbuf 2*2048
    float* red  = S + 16384;    // 32
    float* mi   = S + 16416;    // 16

    {
        float v[8];
        #pragma unroll
        for (int r = 0; r < 8; ++r) v[r] = fabsf(Ab[(size_t)(i0 + r) * 256 + t]);
        *(float4*)&absA[t * 8]     = make_float4(v[0], v[1], v[2], v[3]);
        *(float4*)&absA[t * 8 + 4] = make_float4(v[4], v[5], v[6], v[7]);
    }
    #pragma unroll
    for (int rnd = 0; rnd < 4; ++rnd) {
        int idx = rnd * 256 + t;
        gld16(H2b + idx * 4, &ht[idx * 4]);
    }
    __syncthreads();
    float acc[32];
    #pragma unroll
    for (int i = 0; i < 32; ++i) acc[i] = 0.f;
    #pragma unroll 1
    for (int tl = 0; tl < 8; ++tl) {
        const int buf = tl & 1;
        if (tl < 7) {
            #pragma unroll
            for (int rnd = 0; rnd < 4; ++rnd) {
                int idx = rnd * 256 + t;
                gld16(H2b + (tl + 1) * 4096 + idx * 4, &ht[(buf ^ 1) * 4096 + idx * 4]);
            }
        }
        const float* hb = &ht[buf * 4096];
        #pragma unroll
        for (int jj = 0; jj < 4; ++jj) {
            int jL = u * 4 + jj;
            int j  = tl * 32 + jL;
            float4 h4 = *(const float4*)&hb[jL * 128 + q * 4];
            float hc[4] = {h4.x, h4.y, h4.z, h4.w};
            float4 aA = *(const float4*)&absA[j * 8];
            float4 aB = *(const float4*)&absA[j * 8 + 4];
            float ar[8] = {aA.x, aA.y, aA.z, aA.w, aB.x, aB.y, aB.z, aB.w};
            #pragma unroll
            for (int r = 0; r < 8; ++r)
                #pragma unroll
                for (int c = 0; c < 4; ++c)
                    acc[r * 4 + c] = fmaf(ar[r], hc[c], acc[r * 4 + c]);
        }
        __syncthreads();
    }
    #pragma unroll
    for (int r = 0; r < 8; ++r)
        *(float4*)&part[u * 1024 + r * 128 + q * 4] =
            make_float4(acc[r*4+0], acc[r*4+1], acc[r*4+2], acc[r*4+3]);
    #pragma unroll
    for (int rnd = 0; rnd < 2; ++rnd) {
        int idx = rnd * 256 + t;
        gld16(law + idx * 4, &Wt[idx * 4]);
    }
    __syncthreads();
    float x[8];
    if (t < 128) {
        const int wv = t >> 6;
        #pragma unroll
        for (int r = 0; r < 8; ++r) {
            float s = 0.f;
            #pragma unroll
            for (int uu = 0; uu < 8; ++uu) s += part[uu * 1024 + r * 128 + t];
            x[r] = s;
        }
        #pragma unroll
        for (int r = 0; r < 8; ++r) {
            float s = x[r], s2 = x[r] * x[r];
            #pragma unroll
            for (int o = 32; o > 0; o >>= 1) {
                s  += __shfl_down(s, o, 64);
                s2 += __shfl_down(s2, o, 64);
            }
            if ((t & 63) == 0) { red[r * 4 + wv * 2] = s; red[r * 4 + wv * 2 + 1] = s2; }
        }
    }
    __syncthreads();
    if (t < 8) {
        float s  = red[t * 4] + red[t * 4 + 2];
        float s2 = red[t * 4 + 1] + red[t * 4 + 3];
        float m = s * (1.f / 128.f);
        float v = s2 * (1.f / 128.f) - m * m;
        mi[t * 2] = m;
        mi[t * 2 + 1] = rsqrtf(v + 1e-5f);
    }
    __syncthreads();
    if (t < 128) {
        float gf = g[t], bf = bta[t];
        #pragma unroll
        for (int r = 0; r < 8; ++r)
            xq[t * 8 + r] = fmaxf((x[r] - mi[r * 2]) * mi[r * 2 + 1] * gf + bf, 0.f);
    }
    __syncthreads();
    float u1[32];
    #pragma unroll
    for (int i = 0; i < 32; ++i) u1[i] = 0.f;
    #pragma unroll 1
    for (int kt = 0; kt < 8; ++kt) {
        const int buf = kt & 1;
        if (kt < 7) {
            #pragma unroll
            for (int rnd = 0; rnd < 2; ++rnd) {
                int idx = rnd * 256 + t;
                gld16(law + (kt + 1) * 2048 + idx * 4, &Wt[(buf ^ 1) * 2048 + idx * 4]);
            }
        }
        const float* wt = &Wt[buf * 2048];
        #pragma unroll
        for (int kk = 0; kk < 2; ++kk) {
            int kl = u * 2 + kk;
            int k  = kt * 16 + kl;
            float4 w4 = *(const float4*)&wt[kl * 128 + q * 4];
            float wc[4] = {w4.x, w4.y, w4.z, w4.w};
            float4 xA = *(const float4*)&xq[k * 8];
            float4 xB = *(const float4*)&xq[k * 8 + 4];
            float xr[8] = {xA.x, xA.y, xA.z, xA.w, xB.x, xB.y, xB.z, xB.w};
            #pragma unroll
            for (int r = 0; r < 8; ++r)
                #pragma unroll
                for (int c = 0; c < 4; ++c)
                    u1[r * 4 + c] = fmaf(xr[r], wc[c], u1[r * 4 + c]);
        }
        __syncthreads();
    }
    #pragma unroll
    for (int r = 0; r < 8; ++r)
        *(float4*)&part[u * 1024 + r * 128 + q * 4] =
            make_float4(u1[r*4+0], u1[r*4+1], u1[r*4+2], u1[r*4+3]);
    #pragma unroll
    for (int rnd = 0; rnd < 2; ++rnd) {
        int idx = rnd * 256 + t;
        gld16(lbw + idx * 4, &Wt[idx * 4]);
    }
    __syncthreads();
    if (t < 128) {
        float bb = lab[t];
        #pragma unroll
        for (int r = 0; r < 8; ++r) {
            float s = bb;
            #pragma unroll
            for (int uu = 0; uu < 8; ++uu) s += part[uu * 1024 + r * 128 + t];
            uq[t * 8 + r] = fmaxf(s, 0.f);
        }
    }
    __syncthreads();
    float u2[32];
    #pragma unroll
    for (int i = 0; i < 32; ++i) u2[i] = 0.f;
    #pragma unroll 1
    for (int kt = 0; kt < 8; ++kt) {
        const int buf = kt & 1;
        if (kt < 7) {
            #pragma unroll
            for (int rnd = 0; rnd < 2; ++rnd) {
                int idx = rnd * 256 + t;
                gld16(lbw + (kt + 1) * 2048 + idx * 4, &Wt[(buf ^ 1) * 2048 + idx * 4]);
            }
        }
        const float* wt = &Wt[buf * 2048];
        #pragma unroll
        for (int kk = 0; kk < 2; ++kk) {
            int kl = u * 2 + kk;
            int k  = kt * 16 + kl;
            float4 w4 = *(const float4*)&wt[kl * 128 + q * 4];
            float wc[4] = {w4.x, w4.y, w4.z, w4.w};
            float4 xA = *(const float4*)&uq[k * 8];
            float4 xB = *(const float4*)&uq[k * 8 + 4];
            float xr[8] = {xA.x, xA.y, xA.z, xA.w, xB.x, xB.y, xB.z, xB.w};
            #pragma unroll
            for (int r = 0; r < 8; ++r)
                #pragma unroll
                for (int c = 0; c < 4; ++c)
                    u2[r * 4 + c] = fmaf(xr[r], wc[c], u2[r * 4 + c]);
        }
        __syncthreads();
    }
    #pragma unroll
    for (int r = 0; r < 8; ++r)
        *(float4*)&part[u * 1024 + r * 128 + q * 4] =
            make_float4(u2[r*4+0], u2[r*4+1], u2[r*4+2], u2[r*4+3]);
    __syncthreads();
    #pragma unroll
    for (int e = 0; e < 4; ++e) {
        int idx = e * 256 + t;
        int r = idx >> 7, f = idx & 127;
        float s = lbb[f];
        #pragma unroll
        for (int uu = 0; uu < 8; ++uu) s += part[uu * 1024 + r * 128 + f];
        size_t o = (size_t)(i0 + r) * 128 + f;
        Hb[o] = Hb[o] + s;
    }
    __syncthreads();
}

// ---------------------------------------------------------------------------
__global__ __launch_bounds__(256) void k_mega(Params P) {
    __shared__ __align__(16) float S[21504];   // 84 KB -> 1 block/CU
    const int blk = blockIdx.x;
    const int t = threadIdx.x, q = t & 31, u = t >> 5;
    const int b  = blk >> 5;
    const int c0 = (blk & 31) * 8;
    const int r0 = blk * 8;

    // ------------------------------- embed ---------------------------------
    {
        float* w1s = S;
        float* part = S;
        float* h1q = S + 8192;
        float* w2t = S + 9216;
        float* xq  = S + 13312;
        #pragma unroll
        for (int rnd = 0; rnd < 8; ++rnd) {
            int idx = rnd * 256 + t;
            gld16(P.e1w + idx * 4, &w1s[idx * 4]);
        }
        #pragma unroll
        for (int e = 0; e < 2; ++e) {
            int idx = e * 256 + t;
            int k = idx >> 3, r = idx & 7;
            xq[k * 8 + r] = P.X[(size_t)(r0 + r) * 64 + k];
        }
        __syncthreads();
        float acc[32];
        #pragma unroll
        for (int i = 0; i < 32; ++i) acc[i] = 0.f;
        #pragma unroll
        for (int kk = 0; kk < 8; ++kk) {
            int k = u * 8 + kk;
            float4 w4 = *(const float4*)&w1s[k * 128 + q * 4];
            float wc[4] = {w4.x, w4.y, w4.z, w4.w};
            float4 xA = *(const float4*)&xq[k * 8];
            float4 xB = *(const float4*)&xq[k * 8 + 4];
            float xr[8] = {xA.x, xA.y, xA.z, xA.w, xB.x, xB.y, xB.z, xB.w};
            #pragma unroll
            for (int r = 0; r < 8; ++r)
                #pragma unroll
                for (int c = 0; c < 4; ++c)
                    acc[r * 4 + c] = fmaf(xr[r], wc[c], acc[r * 4 + c]);
        }
        __syncthreads();
        #pragma unroll
        for (int r = 0; r < 8; ++r)
            *(float4*)&part[u * 1024 + r * 128 + q * 4] =
                make_float4(acc[r*4+0], acc[r*4+1], acc[r*4+2], acc[r*4+3]);
        #pragma unroll
        for (int rnd = 0; rnd < 2; ++rnd) {
            int idx = rnd * 256 + t;
            gld16(P.e2w + idx * 4, &w2t[idx * 4]);
        }
        __syncthreads();
        #pragma unroll
        for (int e = 0; e < 4; ++e) {
            int idx = e * 256 + t;
            int f = idx >> 3, r = idx & 7;
            float s = P.e1b[f];
            #pragma unroll
            for (int uu = 0; uu < 8; ++uu) s += part[uu * 1024 + r * 128 + f];
            h1q[f * 8 + r] = fmaxf(s, 0.f);
        }
        __syncthreads();
        float a2[32];
        #pragma unroll
        for (int i = 0; i < 32; ++i) a2[i] = 0.f;
        #pragma unroll 1
        for (int kt = 0; kt < 8; ++kt) {
            const int buf = kt & 1;
            if (kt < 7) {
                #pragma unroll
                for (int rnd = 0; rnd < 2; ++rnd) {
                    int idx = rnd * 256 + t;
                    gld16(P.e2w + (kt + 1) * 2048 + idx * 4,
                          &w2t[(buf ^ 1) * 2048 + idx * 4]);
                }
            }
            const float* wt = &w2t[buf * 2048];
            #pragma unroll
            for (int kk = 0; kk < 2; ++kk) {
                int kl = u * 2 + kk;
                int k  = kt * 16 + kl;
                float4 w4 = *(const float4*)&wt[kl * 128 + q * 4];
                float wc[4] = {w4.x, w4.y, w4.z, w4.w};
                float4 hA = *(const float4*)&h1q[k * 8];
                float4 hB = *(const float4*)&h1q[k * 8 + 4];
                float hr[8] = {hA.x, hA.y, hA.z, hA.w, hB.x, hB.y, hB.z, hB.w};
                #pragma unroll
                for (int r = 0; r < 8; ++r)
                    #pragma unroll
                    for (int c = 0; c < 4; ++c)
                        a2[r * 4 + c] = fmaf(hr[r], wc[c], a2[r * 4 + c]);
            }
            __syncthreads();
        }
        #pragma unroll
        for (int r = 0; r < 8; ++r)
            *(float4*)&part[u * 1024 + r * 128 + q * 4] =
                make_float4(a2[r*4+0], a2[r*4+1], a2[r*4+2], a2[r*4+3]);
        __syncthreads();
        #pragma unroll
        for (int e = 0; e < 4; ++e) {
            int idx = e * 256 + t;
            int r = idx >> 7, f = idx & 127;
            float s = P.e2b[f];
            #pragma unroll
            for (int uu = 0; uu < 8; ++uu) s += part[uu * 1024 + r * 128 + f];
            P.H[(size_t)(r0 + r) * 128 + f] = s;
        }
    }
    gridbar(P.cnt, 0);

    const float* Ab  = P.A + (size_t)b * 65536;
    float* Hb  = P.H + (size_t)b * 32768;
    float* H2b = P.H2 + (size_t)b * 32768;

    stage_gcn1(S, Ab, Hb, P.rw0, P.rr0, P.rb0, H2b, c0, t, q, u);
    gridbar(P.cnt, 1);
    stage_gcn2(S, Ab, H2b, P.ng, P.nbta, P.law0, P.lab0, P.lbw0, P.lbb0, Hb, c0, t, q, u);
    gridbar(P.cnt, 2);
    stage_gcn1(S, Ab, Hb, P.rw1, P.rr1, P.rb1, H2b, c0, t, q, u);
    gridbar(P.cnt, 3);
    stage_gcn2(S, Ab, H2b, P.ng, P.nbta, P.law1, P.lab1, P.lbw1, P.lbb1, Hb, c0, t, q, u);
    gridbar(P.cnt, 4);

    // ------------------------------ deepset --------------------------------
    {
        const int qd = t & 63, ud = t >> 6;
        float* Wt   = S;            // dbuf 2*4096
        float* hraw = S + 8192;     // 1024 [r*128+k]
        float* ph2  = S + 9216;     // 2048 [r*256+f]
        float* part = S + 11264;    // 4096
        float* hmv  = S + 15360;    // 8
        #pragma unroll
        for (int rnd = 0; rnd < 4; ++rnd) {
            int idx = rnd * 256 + t;
            gld16(P.pw1 + idx * 4, &Wt[idx * 4]);
        }
        gld16(P.H + (size_t)r0 * 128 + t * 4, &hraw[t * 4]);
        if (t < 8) hmv[t] = P.hm[r0 + t];
        __syncthreads();
        float acc[32];
        #pragma unroll
        for (int i = 0; i < 32; ++i) acc[i] = 0.f;
        #pragma unroll 1
        for (int kt = 0; kt < 8; ++kt) {
            const int buf = kt & 1;
            if (kt < 7) {
                #pragma unroll
                for (int rnd = 0; rnd < 4; ++rnd) {
                    int idx = rnd * 256 + t;
                    gld16(P.pw1 + (kt + 1) * 4096 + idx * 4,
                          &Wt[(buf ^ 1) * 4096 + idx * 4]);
                }
            }
            const float* wt = &Wt[buf * 4096];
            #pragma unroll
            for (int kk = 0; kk < 4; ++kk) {
                int kl = ud * 4 + kk;
                int k  = kt * 16 + kl;
                float4 w4 = *(const float4*)&wt[kl * 256 + qd * 4];
                float wc[4] = {w4.x, w4.y, w4.z, w4.w};
                float hr[8];
                #pragma unroll
                for (int r = 0; r < 8; ++r) hr[r] = hraw[r * 128 + k];
                #pragma unroll
                for (int r = 0; r < 8; ++r)
                    #pragma unroll
                    for (int c = 0; c < 4; ++c)
                        acc[r * 4 + c] = fmaf(hr[r], wc[c], acc[r * 4 + c]);
            }
            __syncthreads();
        }
        #pragma unroll
        for (int gg = 0; gg < 2; ++gg) {
            #pragma unroll
            for (int rr = 0; rr < 4; ++rr) {
                int r = gg * 4 + rr;
                *(float4*)&part[ud * 1024 + rr * 256 + qd * 4] =
                    make_float4(acc[r*4+0], acc[r*4+1], acc[r*4+2], acc[r*4+3]);
            }
            __syncthreads();
            #pragma unroll
            for (int e = 0; e < 4; ++e) {
                int idx = e * 256 + t;
                int rr = idx >> 8, f = idx & 255;
                float s = P.pb1[f];
                #pragma unroll
                for (int uu = 0; uu < 4; ++uu) s += part[uu * 1024 + rr * 256 + f];
                ph2[(gg * 4 + rr) * 256 + f] = fmaxf(s, 0.f);
            }
            __syncthreads();
        }
        #pragma unroll
        for (int rnd = 0; rnd < 4; ++rnd) {
            int idx = rnd * 256 + t;
            gld16(P.pw2 + idx * 4, &Wt[idx * 4]);
        }
        __syncthreads();
        float a2[32];
        #pragma unroll
        for (int i = 0; i < 32; ++i) a2[i] = 0.f;
        #pragma unroll 1
        for (int kt = 0; kt < 16; ++kt) {
            const int buf = kt & 1;
            if (kt < 15) {
                #pragma unroll
                for (int rnd = 0; rnd < 4; ++rnd) {
                    int idx = rnd * 256 + t;
                    gld16(P.pw2 + (kt + 1) * 4096 + idx * 4,
                          &Wt[(buf ^ 1) * 4096 + idx * 4]);
                }
            }
            const float* wt = &Wt[buf * 4096];
            #pragma unroll
            for (int kk = 0; kk < 4; ++kk) {
                int kl = ud * 4 + kk;
                int k  = kt * 16 + kl;
                float4 w4 = *(const float4*)&wt[kl * 256 + qd * 4];
                float wc[4] = {w4.x, w4.y, w4.z, w4.w};
                float pr[8];
                #pragma unroll
                for (int r = 0; r < 8; ++r) pr[r] = ph2[r * 256 + k];
                #pragma unroll
                for (int r = 0; r < 8; ++r)
                    #pragma unroll
                    for (int c = 0; c < 4; ++c)
                        a2[r * 4 + c] = fmaf(pr[r], wc[c], a2[r * 4 + c]);
            }
            __syncthreads();
        }
        float hp = 0.f, sp = 0.f;
        #pragma unroll
        for (int gg = 0; gg < 2; ++gg) {
            #pragma unroll
            for (int rr = 0; rr < 4; ++rr) {
                int r = gg * 4 + rr;
                *(float4*)&part[ud * 1024 + rr * 256 + qd * 4] =
                    make_float4(a2[r*4+0], a2[r*4+1], a2[r*4+2], a2[r*4+3]);
            }
            __syncthreads();
            {
                float bb = P.pb2[t];
                #pragma unroll
                for (int rr = 0; rr < 4; ++rr) {
                    float s = bb;
                    #pragma unroll
                    for (int uu = 0; uu < 4; ++uu) s += part[uu * 1024 + rr * 256 + t];
                    float p = fmaxf(s, 0.f);
                    sp += p;
                    hp = fmaf(p, hmv[gg * 4 + rr], hp);
                }
            }
            __syncthreads();
        }
        atomicAdd(&P.hsum[b * 256 + t], hp);
        atomicAdd(&P.asum[b * 256 + t], sp - hp);
    }
    gridbar(P.cnt, 5);

    // -------------------------------- rho ----------------------------------
    if (blk < NB) {
        float* Wt   = S;            // dbuf 2*4096
        float* sv   = S + 8192;     // 512
        float* part = S + 8704;     // 2048
        float* wsv  = S + 10752;    // 2
        #pragma unroll
        for (int rnd = 0; rnd < 4; ++rnd) {
            int idx = rnd * 256 + t;
            gld16(P.qw1 + idx * 4, &Wt[idx * 4]);
        }
        sv[t]       = P.hsum[blk * 256 + t];
        sv[256 + t] = P.asum[blk * 256 + t];
        __syncthreads();
        float aH[4] = {0.f, 0.f, 0.f, 0.f}, aA[4] = {0.f, 0.f, 0.f, 0.f};
        #pragma unroll 1
        for (int kt = 0; kt < 8; ++kt) {
            const int buf = kt & 1;
            if (kt < 7) {
                #pragma unroll
                for (int rnd = 0; rnd < 4; ++rnd) {
                    int idx = rnd * 256 + t;
                    gld16(P.qw1 + (kt + 1) * 4096 + idx * 4,
                          &Wt[(buf ^ 1) * 4096 + idx * 4]);
                }
            }
            const float* wt = &Wt[buf * 4096];
            #pragma unroll
            for (int kk = 0; kk < 4; ++kk) {
                int kl = u * 4 + kk;
                int k  = kt * 32 + kl;
                float4 w4 = *(const float4*)&wt[kl * 128 + q * 4];
                float sh = sv[k], sa = sv[256 + k];
                aH[0] = fmaf(sh, w4.x, aH[0]); aA[0] = fmaf(sa, w4.x, aA[0]);
                aH[1] = fmaf(sh, w4.y, aH[1]); aA[1] = fmaf(sa, w4.y, aA[1]);
                aH[2] = fmaf(sh, w4.z, aH[2]); aA[2] = fmaf(sa, w4.z, aA[2]);
                aH[3] = fmaf(sh, w4.w, aH[3]); aA[3] = fmaf(sa, w4.w, aA[3]);
            }
            __syncthreads();
        }
        *(float4*)&part[u * 256 + q * 4]       = make_float4(aH[0], aH[1], aH[2], aH[3]);
        *(float4*)&part[u * 256 + 128 + q * 4] = make_float4(aA[0], aA[1], aA[2], aA[3]);
        __syncthreads();
        if (t < 64) {
            int vec = t >> 5, fq = t & 31;
            float4 s = make_float4(0.f, 0.f, 0.f, 0.f);
            #pragma unroll
            for (int uu = 0; uu < 8; ++uu) {
                float4 p = *(const float4*)&part[uu * 256 + vec * 128 + fq * 4];
                s.x += p.x; s.y += p.y; s.z += p.z; s.w += p.w;
            }
            float4 bb  = *(const float4*)&P.qb1[fq * 4];
            float4 w2q = *(const float4*)&P.qw2[fq * 4];
            float p = fmaxf(s.x + bb.x, 0.f) * w2q.x
                    + fmaxf(s.y + bb.y, 0.f) * w2q.y
                    + fmaxf(s.z + bb.z, 0.f) * w2q.z
                    + fmaxf(s.w + bb.w, 0.f) * w2q.w;
            #pragma unroll
            for (int o = 16; o > 0; o >>= 1) p += __shfl_down(p, o, 32);
            if ((t & 31) == 0) wsv[vec] = p;
        }
        __syncthreads();
        if (t == 0)
            P.outp[blk] = 0.5f + 0.5f * tanhf(wsv[0] - wsv[1]);
    }
}

// ---------------------------------------------------------------------------
extern "C" void kernel_launch(void* const* d_in, const int* in_sizes, int n_in,
                              void* d_out, int out_size, void* d_ws, size_t ws_size,
                              hipStream_t stream) {
    float* ws = (float*)d_ws;
    Params P;
    P.A    = (const float*)d_in[0];
    P.X    = (const float*)d_in[1];
    P.hm   = (const float*)d_in[2];
    P.e1w  = (const float*)d_in[3];
    P.e1b  = (const float*)d_in[4];
    P.e2w  = (const float*)d_in[5];
    P.e2b  = (const float*)d_in[6];
    P.rw0  = (const float*)d_in[7];
    P.rr0  = (const float*)d_in[8];
    P.rb0  = (const float*)d_in[9];
    P.law0 = (const float*)d_in[10];
    P.lab0 = (const float*)d_in[11];
    P.lbw0 = (const float*)d_in[12];
    P.lbb0 = (const float*)d_in[13];
    P.rw1  = (const float*)d_in[14];
    P.rr1  = (const float*)d_in[15];
    P.rb1  = (const float*)d_in[16];
    P.law1 = (const float*)d_in[17];
    P.lab1 = (const float*)d_in[18];
    P.lbw1 = (const float*)d_in[19];
    P.lbb1 = (const float*)d_in[20];
    P.ng   = (const float*)d_in[21];
    P.nbta = (const float*)d_in[22];
    P.pw1  = (const float*)d_in[23];
    P.pb1  = (const float*)d_in[24];
    P.pw2  = (const float*)d_in[25];
    P.pb2  = (const float*)d_in[26];
    P.qw1  = (const float*)d_in[27];
    P.qb1  = (const float*)d_in[28];
    P.qw2  = (const float*)d_in[29];
    P.qb2  = (const float*)d_in[30];
    P.H    = ws;                    // 262144
    P.H2   = ws + 262144;           // 262144
    P.hsum = ws + 524288;           // 2048
    P.asum = ws + 526336;           // 2048
    P.cnt  = (int*)(ws + 528384);   // 16 ints
    P.outp = (float*)d_out;

    k_init<<<17, 256, 0, stream>>>(P.hsum, P.cnt);
    k_mega<<<GRID, 256, 0, stream>>>(P);
}

// Round 9
// 268.873 us; speedup vs baseline: 1.1226x; 1.1226x over previous
//
#include <hip/hip_runtime.h>
#include <math.h>

// Shapes: B=8, N=256, NID=64, V=GH=128, PHI=256, RHO=128
#define NB 8
#define GRID 256
#define NT 512

typedef __attribute__((address_space(1))) const void* gas1p;
typedef __attribute__((address_space(3))) void* las3p;
static __device__ __forceinline__ void gld16(const float* g, float* l) {
    __builtin_amdgcn_global_load_lds((gas1p)g, (las3p)l, 16, 0, 0);
}

struct Params {
    const float *A, *X, *hm;
    const float *e1w, *e1b, *e2w, *e2b;
    const float *rw0, *rr0, *rb0, *law0, *lab0, *lbw0, *lbb0;
    const float *rw1, *rr1, *rb1, *law1, *lab1, *lbw1, *lbb1;
    const float *ng, *nbta;
    const float *pw1, *pb1, *pw2, *pb2;
    const float *qw1, *qb1, *qw2, *qb2;
    float *H, *H2, *hsum, *asum, *outp;
    int *cnt;
};

__global__ __launch_bounds__(256) void k_init(float* pools, int* cnt) {
    int i = blockIdx.x * 256 + threadIdx.x;
    if (i < 4096) pools[i] = 0.f;
    if (blockIdx.x == 16 && threadIdx.x < 16) cnt[threadIdx.x] = 0;
}

__device__ __forceinline__ void gridbar(int* cnt, int id) {
    __syncthreads();
    if (threadIdx.x == 0) {
        __threadfence();
        __hip_atomic_fetch_add(&cnt[id], 1, __ATOMIC_RELAXED, __HIP_MEMORY_SCOPE_AGENT);
        while (__hip_atomic_load(&cnt[id], __ATOMIC_RELAXED,
                                 __HIP_MEMORY_SCOPE_AGENT) < GRID)
            __builtin_amdgcn_s_sleep(4);
        __threadfence();
    }
    __syncthreads();
}

#define FMA44(ACC, AR, WC)                                        \
    _Pragma("unroll")                                             \
    for (int _r = 0; _r < 4; ++_r)                                \
        _Pragma("unroll")                                         \
        for (int _c = 0; _c < 4; ++_c)                            \
            ACC[_r * 4 + _c] = fmaf(AR[_r], WC[_c], ACC[_r * 4 + _c]);

// ---------------------------------------------------------------------------
// gcn1: relation-mean aggregation (K=256 over i) + 3-matrix RGCN linear
// (stacked K=384). Block owns 8 targets j0..j0+7 of batch b.
// ---------------------------------------------------------------------------
__device__ void stage_gcn1(float* S, float* cntp, float* cntk,
        const float* Ag, const float* Hg,
        const float* Wrel, const float* Wroot, const float* bias,
        float* H2g, int j0, int t) {
    const int q5 = t & 31;
    const int u4 = (t >> 5) & 3, v4 = t >> 7;   // phase A: 4 K-slices x 4 row-grps
    const int u8 = (t >> 5) & 7, v2 = t >> 8;   // phase B: 8 K-slices x 2 row-grps
    float* HbS  = S;            // 32768 (staged H, whole batch)
    float* mT   = S + 32768;    // 4096 masks [i*16 + rel*8 + jl]
    float* part = S;            // 8192 phase-A partials (Hb dead)
    float* pb3  = S + 32768;    // 3072 stacked acts [k3*8 + r] (masks dead)
    float* WC   = S;            // 32768 phase-B weights
    float* pB   = S + 16384;    // 8192 phase-B partials

    #pragma unroll
    for (int rnd = 0; rnd < 16; ++rnd) {
        int idx = rnd * NT + t;
        gld16(Hg + idx * 4, &HbS[idx * 4]);
    }
    if (t < 256) {
        float4 a0 = *(const float4*)(Ag + (size_t)t * 256 + j0);
        float4 a1 = *(const float4*)(Ag + (size_t)t * 256 + j0 + 4);
        *(float4*)&mT[t * 16] = make_float4(
            (a0.x < 0.f) ? 1.f : 0.f, (a0.y < 0.f) ? 1.f : 0.f,
            (a0.z < 0.f) ? 1.f : 0.f, (a0.w < 0.f) ? 1.f : 0.f);
        *(float4*)&mT[t * 16 + 4] = make_float4(
            (a1.x < 0.f) ? 1.f : 0.f, (a1.y < 0.f) ? 1.f : 0.f,
            (a1.z < 0.f) ? 1.f : 0.f, (a1.w < 0.f) ? 1.f : 0.f);
        *(float4*)&mT[t * 16 + 8] = make_float4(
            (a0.x > 0.f) ? 1.f : 0.f, (a0.y > 0.f) ? 1.f : 0.f,
            (a0.z > 0.f) ? 1.f : 0.f, (a0.w > 0.f) ? 1.f : 0.f);
        *(float4*)&mT[t * 16 + 12] = make_float4(
            (a1.x > 0.f) ? 1.f : 0.f, (a1.y > 0.f) ? 1.f : 0.f,
            (a1.z > 0.f) ? 1.f : 0.f, (a1.w > 0.f) ? 1.f : 0.f);
    }
    __syncthreads();
    {   // mask counts: 32 chunks x 16 slots
        int chunk = t >> 4, slot = t & 15;
        float c = 0.f;
        #pragma unroll
        for (int qq = 0; qq < 8; ++qq) c += mT[(chunk * 8 + qq) * 16 + slot];
        cntp[slot * 32 + chunk] = c;
    }
    // phase A: zero barriers inside
    float acc[16];
    #pragma unroll
    for (int i = 0; i < 16; ++i) acc[i] = 0.f;
    #pragma unroll 8
    for (int ii = 0; ii < 64; ++ii) {
        int i = u4 * 64 + ii;
        float4 w4 = *(const float4*)&HbS[i * 128 + q5 * 4];
        float4 a4 = *(const float4*)&mT[i * 16 + v4 * 4];
        float wc[4] = {w4.x, w4.y, w4.z, w4.w};
        float ar[4] = {a4.x, a4.y, a4.z, a4.w};
        FMA44(acc, ar, wc)
    }
    __syncthreads();
    if (t < 16) {
        float s = 0.f;
        #pragma unroll
        for (int c = 0; c < 32; ++c) s += cntp[t * 32 + c];
        cntk[t] = s;
    }
    // root rows from global into pb3 (masks region now dead)
    #pragma unroll
    for (int e = 0; e < 2; ++e) {
        int idx = e * NT + t;
        int r = idx >> 7, k = idx & 127;
        pb3[k * 8 + r] = Hg[(size_t)(j0 + r) * 128 + k];
    }
    // phase-A partials (Hb head dead)
    #pragma unroll
    for (int rr = 0; rr < 4; ++rr)
        *(float4*)&part[u4 * 2048 + (v4 * 4 + rr) * 128 + q5 * 4] =
            make_float4(acc[rr*4+0], acc[rr*4+1], acc[rr*4+2], acc[rr*4+3]);
    __syncthreads();
    // means -> pb3
    #pragma unroll
    for (int e = 0; e < 4; ++e) {
        int idx = e * NT + t;
        int s16 = idx >> 7, k = idx & 127;
        int rel = s16 >> 3, jl = s16 & 7;
        float v = 0.f;
        #pragma unroll
        for (int uu = 0; uu < 4; ++uu) v += part[uu * 2048 + s16 * 128 + k];
        pb3[((rel + 1) * 128 + k) * 8 + jl] = v / fmaxf(cntk[s16], 1.f);
    }
    __syncthreads();
    // stage Wroot|W0 (128 KB)
    #pragma unroll
    for (int rnd = 0; rnd < 8; ++rnd) {
        int idx = rnd * NT + t;
        gld16(Wroot + idx * 4, &WC[idx * 4]);
        gld16(Wrel + idx * 4, &WC[16384 + idx * 4]);
    }
    __syncthreads();
    float bcc[16];
    #pragma unroll
    for (int i = 0; i < 16; ++i) bcc[i] = 0.f;
    #pragma unroll 8
    for (int kk = 0; kk < 32; ++kk) {            // k3 = 0..255 (root | m0)
        int k3 = u8 * 32 + kk;
        float4 w4 = *(const float4*)&WC[k3 * 128 + q5 * 4];
        float4 a4 = *(const float4*)&pb3[k3 * 8 + v2 * 4];
        float wc[4] = {w4.x, w4.y, w4.z, w4.w};
        float ar[4] = {a4.x, a4.y, a4.z, a4.w};
        FMA44(bcc, ar, wc)
    }
    __syncthreads();
    #pragma unroll
    for (int rnd = 0; rnd < 8; ++rnd) {          // stage W1 (64 KB)
        int idx = rnd * NT + t;
        gld16(Wrel + 16384 + idx * 4, &WC[idx * 4]);
    }
    __syncthreads();
    #pragma unroll 8
    for (int kk = 0; kk < 16; ++kk) {            // k3 = 256..383 (m1)
        int k3 = 256 + u8 * 16 + kk;
        float4 w4 = *(const float4*)&WC[(k3 - 256) * 128 + q5 * 4];
        float4 a4 = *(const float4*)&pb3[k3 * 8 + v2 * 4];
        float wc[4] = {w4.x, w4.y, w4.z, w4.w};
        float ar[4] = {a4.x, a4.y, a4.z, a4.w};
        FMA44(bcc, ar, wc)
    }
    __syncthreads();
    #pragma unroll
    for (int rr = 0; rr < 4; ++rr)
        *(float4*)&pB[u8 * 1024 + (v2 * 4 + rr) * 128 + q5 * 4] =
            make_float4(bcc[rr*4+0], bcc[rr*4+1], bcc[rr*4+2], bcc[rr*4+3]);
    __syncthreads();
    #pragma unroll
    for (int e = 0; e < 2; ++e) {
        int idx = e * NT + t;
        int r = idx >> 7, f = idx & 127;
        float s = bias[f];
        #pragma unroll
        for (int uu = 0; uu < 8; ++uu) s += pB[uu * 1024 + r * 128 + f];
        H2g[(size_t)(j0 + r) * 128 + f] = s;
    }
    __syncthreads();
}

// ---------------------------------------------------------------------------
// gcn2: |A|-agg (K=256 over j) + LN + MLP(128->128->128) + H-update
// ---------------------------------------------------------------------------
__device__ void stage_gcn2(float* S, float* red, float* mi,
        const float* Ag, const float* H2g,
        const float* g, const float* bta, const float* law, const float* lab,
        const float* lbw, const float* lbb, float* Hg, int i0, int t) {
    const int q5 = t & 31;
    const int u8 = (t >> 5) & 7, v2 = t >> 8;
    float* H2S  = S;            // 32768
    float* absT = S + 32768;    // 2048 [j*8 + r]
    float* part = S;            // 8192
    float* WS   = S + 8192;     // 16384 (law then lbw)
    float* xqT  = S + 24576;    // 1024 [k*8 + r]
    float* uqT  = S + 25600;    // 1024

    #pragma unroll
    for (int rnd = 0; rnd < 16; ++rnd) {
        int idx = rnd * NT + t;
        gld16(H2g + idx * 4, &H2S[idx * 4]);
    }
    #pragma unroll
    for (int e = 0; e < 4; ++e) {
        int idx = e * NT + t;
        int j = idx & 255, r = idx >> 8;
        absT[j * 8 + r] = fabsf(Ag[(size_t)(i0 + r) * 256 + j]);
    }
    __syncthreads();
    float acc[16];
    #pragma unroll
    for (int i = 0; i < 16; ++i) acc[i] = 0.f;
    #pragma unroll 8
    for (int jj = 0; jj < 32; ++jj) {
        int j = u8 * 32 + jj;
        float4 w4 = *(const float4*)&H2S[j * 128 + q5 * 4];
        float4 a4 = *(const float4*)&absT[j * 8 + v2 * 4];
        float wc[4] = {w4.x, w4.y, w4.z, w4.w};
        float ar[4] = {a4.x, a4.y, a4.z, a4.w};
        FMA44(acc, ar, wc)
    }
    __syncthreads();
    #pragma unroll
    for (int rr = 0; rr < 4; ++rr)
        *(float4*)&part[u8 * 1024 + (v2 * 4 + rr) * 128 + q5 * 4] =
            make_float4(acc[rr*4+0], acc[rr*4+1], acc[rr*4+2], acc[rr*4+3]);
    #pragma unroll
    for (int rnd = 0; rnd < 8; ++rnd) {          // stage law (disjoint region)
        int idx = rnd * NT + t;
        gld16(law + idx * 4, &WS[idx * 4]);
    }
    __syncthreads();
    float x[8];
    if (t < 128) {
        const int wv = t >> 6;
        #pragma unroll
        for (int r = 0; r < 8; ++r) {
            float s = 0.f;
            #pragma unroll
            for (int uu = 0; uu < 8; ++uu) s += part[uu * 1024 + r * 128 + t];
            x[r] = s;
        }
        #pragma unroll
        for (int r = 0; r < 8; ++r) {
            float s = x[r], s2 = x[r] * x[r];
            #pragma unroll
            for (int o = 32; o > 0; o >>= 1) {
                s  += __shfl_down(s, o, 64);
                s2 += __shfl_down(s2, o, 64);
            }
            if ((t & 63) == 0) { red[r * 4 + wv * 2] = s; red[r * 4 + wv * 2 + 1] = s2; }
        }
    }
    __syncthreads();
    if (t < 8) {
        float s  = red[t * 4] + red[t * 4 + 2];
        float s2 = red[t * 4 + 1] + red[t * 4 + 3];
        float m = s * (1.f / 128.f);
        float v = s2 * (1.f / 128.f) - m * m;
        mi[t * 2] = m;
        mi[t * 2 + 1] = rsqrtf(v + 1e-5f);
    }
    __syncthreads();
    if (t < 128) {
        float gf = g[t], bf = bta[t];
        #pragma unroll
        for (int r = 0; r < 8; ++r)
            xqT[t * 8 + r] = fmaxf((x[r] - mi[r * 2]) * mi[r * 2 + 1] * gf + bf, 0.f);
    }
    __syncthreads();
    float u1[16];
    #pragma unroll
    for (int i = 0; i < 16; ++i) u1[i] = 0.f;
    #pragma unroll 8
    for (int kk = 0; kk < 16; ++kk) {
        int k = u8 * 16 + kk;
        float4 w4 = *(const float4*)&WS[k * 128 + q5 * 4];
        float4 a4 = *(const float4*)&xqT[k * 8 + v2 * 4];
        float wc[4] = {w4.x, w4.y, w4.z, w4.w};
        float ar[4] = {a4.x, a4.y, a4.z, a4.w};
        FMA44(u1, ar, wc)
    }
    __syncthreads();
    #pragma unroll
    for (int rr = 0; rr < 4; ++rr)
        *(float4*)&part[u8 * 1024 + (v2 * 4 + rr) * 128 + q5 * 4] =
            make_float4(u1[rr*4+0], u1[rr*4+1], u1[rr*4+2], u1[rr*4+3]);
    #pragma unroll
    for (int rnd = 0; rnd < 8; ++rnd) {          // stage lbw
        int idx = rnd * NT + t;
        gld16(lbw + idx * 4, &WS[idx * 4]);
    }
    __syncthreads();
    if (t < 128) {
        float bb = lab[t];
        #pragma unroll
        for (int r = 0; r < 8; ++r) {
            float s = bb;
            #pragma unroll
            for (int uu = 0; uu < 8; ++uu) s += part[uu * 1024 + r * 128 + t];
            uqT[t * 8 + r] = fmaxf(s, 0.f);
        }
    }
    __syncthreads();
    float u2[16];
    #pragma unroll
    for (int i = 0; i < 16; ++i) u2[i] = 0.f;
    #pragma unroll 8
    for (int kk = 0; kk < 16; ++kk) {
        int k = u8 * 16 + kk;
        float4 w4 = *(const float4*)&WS[k * 128 + q5 * 4];
        float4 a4 = *(const float4*)&uqT[k * 8 + v2 * 4];
        float wc[4] = {w4.x, w4.y, w4.z, w4.w};
        float ar[4] = {a4.x, a4.y, a4.z, a4.w};
        FMA44(u2, ar, wc)
    }
    __syncthreads();
    #pragma unroll
    for (int rr = 0; rr < 4; ++rr)
        *(float4*)&part[u8 * 1024 + (v2 * 4 + rr) * 128 + q5 * 4] =
            make_float4(u2[rr*4+0], u2[rr*4+1], u2[rr*4+2], u2[rr*4+3]);
    __syncthreads();
    #pragma unroll
    for (int e = 0; e < 2; ++e) {
        int idx = e * NT + t;
        int r = idx >> 7, f = idx & 127;
        float s = lbb[f];
        #pragma unroll
        for (int uu = 0; uu < 8; ++uu) s += part[uu * 1024 + r * 128 + f];
        size_t o = (size_t)(i0 + r) * 128 + f;
        Hg[o] = Hg[o] + s;
    }
    __syncthreads();
}

// ---------------------------------------------------------------------------
__global__ __launch_bounds__(NT) void k_mega(Params P) {
    __shared__ __align__(16) float S[36864];     // 144 KB -> 1 block/CU
    __shared__ float cntp[512], cntk[16], red[32], mi[16], hmv[8], wsv[2];
    const int blk = blockIdx.x;
    const int t = threadIdx.x;
    const int q5 = t & 31;
    const int u8 = (t >> 5) & 7, v2 = t >> 8;
    const int b  = blk >> 5;
    const int c0 = (blk & 31) * 8;
    const int r0 = blk * 8;

    // ------------------------------- embed ---------------------------------
    {
        float* W1s = S;             // 8192
        float* W2s = S + 8192;      // 16384
        float* xqT = S + 24576;     // 512
        float* h1T = S + 25088;     // 1024
        float* part = S + 26112;    // 8192
        #pragma unroll
        for (int rnd = 0; rnd < 4; ++rnd) {
            int idx = rnd * NT + t;
            gld16(P.e1w + idx * 4, &W1s[idx * 4]);
        }
        #pragma unroll
        for (int rnd = 0; rnd < 8; ++rnd) {
            int idx = rnd * NT + t;
            gld16(P.e2w + idx * 4, &W2s[idx * 4]);
        }
        {
            int k = t & 63, r = t >> 6;
            xqT[k * 8 + r] = P.X[(size_t)(r0 + r) * 64 + k];
        }
        __syncthreads();
        float acc[16];
        #pragma unroll
        for (int i = 0; i < 16; ++i) acc[i] = 0.f;
        #pragma unroll 8
        for (int kk = 0; kk < 8; ++kk) {
            int k = u8 * 8 + kk;
            float4 w4 = *(const float4*)&W1s[k * 128 + q5 * 4];
            float4 a4 = *(const float4*)&xqT[k * 8 + v2 * 4];
            float wc[4] = {w4.x, w4.y, w4.z, w4.w};
            float ar[4] = {a4.x, a4.y, a4.z, a4.w};
            FMA44(acc, ar, wc)
        }
        #pragma unroll
        for (int rr = 0; rr < 4; ++rr)
            *(float4*)&part[u8 * 1024 + (v2 * 4 + rr) * 128 + q5 * 4] =
                make_float4(acc[rr*4+0], acc[rr*4+1], acc[rr*4+2], acc[rr*4+3]);
        __syncthreads();
        #pragma unroll
        for (int e = 0; e < 2; ++e) {
            int idx = e * NT + t;
            int r = idx >> 7, f = idx & 127;
            float s = P.e1b[f];
            #pragma unroll
            for (int uu = 0; uu < 8; ++uu) s += part[uu * 1024 + r * 128 + f];
            h1T[f * 8 + r] = fmaxf(s, 0.f);
        }
        __syncthreads();
        float a2[16];
        #pragma unroll
        for (int i = 0; i < 16; ++i) a2[i] = 0.f;
        #pragma unroll 8
        for (int kk = 0; kk < 16; ++kk) {
            int k = u8 * 16 + kk;
            float4 w4 = *(const float4*)&W2s[k * 128 + q5 * 4];
            float4 a4 = *(const float4*)&h1T[k * 8 + v2 * 4];
            float wc[4] = {w4.x, w4.y, w4.z, w4.w};
            float ar[4] = {a4.x, a4.y, a4.z, a4.w};
            FMA44(a2, ar, wc)
        }
        __syncthreads();
        #pragma unroll
        for (int rr = 0; rr < 4; ++rr)
            *(float4*)&part[u8 * 1024 + (v2 * 4 + rr) * 128 + q5 * 4] =
                make_float4(a2[rr*4+0], a2[rr*4+1], a2[rr*4+2], a2[rr*4+3]);
        __syncthreads();
        #pragma unroll
        for (int e = 0; e < 2; ++e) {
            int idx = e * NT + t;
            int r = idx >> 7, f = idx & 127;
            float s = P.e2b[f];
            #pragma unroll
            for (int uu = 0; uu < 8; ++uu) s += part[uu * 1024 + r * 128 + f];
            P.H[(size_t)(r0 + r) * 128 + f] = s;
        }
    }
    gridbar(P.cnt, 0);

    const float* Ag = P.A + (size_t)b * 65536;
    float* Hg  = P.H + (size_t)b * 32768;
    float* H2g = P.H2 + (size_t)b * 32768;

    stage_gcn1(S, cntp, cntk, Ag, Hg, P.rw0, P.rr0, P.rb0, H2g, c0, t);
    gridbar(P.cnt, 1);
    stage_gcn2(S, red, mi, Ag, H2g, P.ng, P.nbta, P.law0, P.lab0, P.lbw0, P.lbb0,
               Hg, c0, t);
    gridbar(P.cnt, 2);
    stage_gcn1(S, cntp, cntk, Ag, Hg, P.rw1, P.rr1, P.rb1, H2g, c0, t);
    gridbar(P.cnt, 3);
    stage_gcn2(S, red, mi, Ag, H2g, P.ng, P.nbta, P.law1, P.lab1, P.lbw1, P.lbb1,
               Hg, c0, t);
    gridbar(P.cnt, 4);

    // ------------------------------ deepset --------------------------------
    {
        const int q6 = t & 63, ud = t >> 6;      // 64 f-quads x 8 K-slices
        float* Ws    = S;           // 32768
        float* hrawT = S + 32768;   // 1024 [k*8 + r]
        float* phT   = S + 33792;   // 2048 [k*8 + r]
        float* part  = S;           // 16384 (8u x 8r x 256f)
        float* pool2 = S + 33792;   // reuse phT (dead) [r*256 + f]
        #pragma unroll
        for (int rnd = 0; rnd < 16; ++rnd) {
            int idx = rnd * NT + t;
            gld16(P.pw1 + idx * 4, &Ws[idx * 4]);
        }
        #pragma unroll
        for (int e = 0; e < 2; ++e) {
            int idx = e * NT + t;
            int k = idx & 127, r = idx >> 7;
            hrawT[k * 8 + r] = P.H[(size_t)(r0 + r) * 128 + k];
        }
        if (t < 8) hmv[t] = P.hm[r0 + t];
        __syncthreads();
        float acc[32];
        #pragma unroll
        for (int i = 0; i < 32; ++i) acc[i] = 0.f;
        #pragma unroll 8
        for (int kk = 0; kk < 16; ++kk) {        // K=128, slice 16
            int k = ud * 16 + kk;
            float4 w4 = *(const float4*)&Ws[k * 256 + q6 * 4];
            float4 aA = *(const float4*)&hrawT[k * 8];
            float4 aB = *(const float4*)&hrawT[k * 8 + 4];
            float wc[4] = {w4.x, w4.y, w4.z, w4.w};
            float ar[8] = {aA.x, aA.y, aA.z, aA.w, aB.x, aB.y, aB.z, aB.w};
            #pragma unroll
            for (int r = 0; r < 8; ++r)
                #pragma unroll
                for (int c = 0; c < 4; ++c)
                    acc[r * 4 + c] = fmaf(ar[r], wc[c], acc[r * 4 + c]);
        }
        __syncthreads();
        #pragma unroll
        for (int r = 0; r < 8; ++r)
            *(float4*)&part[ud * 2048 + r * 256 + q6 * 4] =
                make_float4(acc[r*4+0], acc[r*4+1], acc[r*4+2], acc[r*4+3]);
        __syncthreads();
        #pragma unroll
        for (int e = 0; e < 4; ++e) {
            int idx = e * NT + t;
            int r = idx >> 8, f = idx & 255;
            float s = P.pb1[f];
            #pragma unroll
            for (int uu = 0; uu < 8; ++uu) s += part[uu * 2048 + r * 256 + f];
            phT[f * 8 + r] = fmaxf(s, 0.f);
        }
        __syncthreads();
        float a2[32];
        #pragma unroll
        for (int i = 0; i < 32; ++i) a2[i] = 0.f;
        #pragma unroll
        for (int half = 0; half < 2; ++half) {   // K=256 in 2 staged halves
            #pragma unroll
            for (int rnd = 0; rnd < 16; ++rnd) {
                int idx = rnd * NT + t;
                gld16(P.pw2 + half * 32768 + idx * 4, &Ws[idx * 4]);
            }
            __syncthreads();
            #pragma unroll 8
            for (int kk = 0; kk < 16; ++kk) {
                int kl = ud * 16 + kk;
                int k  = half * 128 + kl;
                float4 w4 = *(const float4*)&Ws[kl * 256 + q6 * 4];
                float4 aA = *(const float4*)&phT[k * 8];
                float4 aB = *(const float4*)&phT[k * 8 + 4];
                float wc[4] = {w4.x, w4.y, w4.z, w4.w};
                float ar[8] = {aA.x, aA.y, aA.z, aA.w, aB.x, aB.y, aB.z, aB.w};
                #pragma unroll
                for (int r = 0; r < 8; ++r)
                    #pragma unroll
                    for (int c = 0; c < 4; ++c)
                        a2[r * 4 + c] = fmaf(ar[r], wc[c], a2[r * 4 + c]);
            }
            __syncthreads();
        }
        #pragma unroll
        for (int r = 0; r < 8; ++r)
            *(float4*)&part[ud * 2048 + r * 256 + q6 * 4] =
                make_float4(a2[r*4+0], a2[r*4+1], a2[r*4+2], a2[r*4+3]);
        __syncthreads();
        #pragma unroll
        for (int e = 0; e < 4; ++e) {
            int idx = e * NT + t;
            int r = idx >> 8, f = idx & 255;
            float s = P.pb2[f];
            #pragma unroll
            for (int uu = 0; uu < 8; ++uu) s += part[uu * 2048 + r * 256 + f];
            pool2[r * 256 + f] = fmaxf(s, 0.f);
        }
        __syncthreads();
        if (t < 256) {
            float hp = 0.f, sp = 0.f;
            #pragma unroll
            for (int r = 0; r < 8; ++r) {
                float p = pool2[r * 256 + t];
                sp += p;
                hp = fmaf(p, hmv[r], hp);
            }
            atomicAdd(&P.hsum[b * 256 + t], hp);
            atomicAdd(&P.asum[b * 256 + t], sp - hp);
        }
    }
    gridbar(P.cnt, 5);

    // -------------------------------- rho ----------------------------------
    if (blk < NB) {
        const int u16 = t >> 5;     // 16 K-slices of 16
        float* Ws = S;              // 32768
        float* sv = S + 32768;      // 512
        float* pR = S;              // 4096 (Ws dead after loop)
        #pragma unroll
        for (int rnd = 0; rnd < 16; ++rnd) {
            int idx = rnd * NT + t;
            gld16(P.qw1 + idx * 4, &Ws[idx * 4]);
        }
        if (t < 256) sv[t] = P.hsum[blk * 256 + t];
        else sv[256 + (t - 256)] = P.asum[blk * 256 + (t - 256)];
        __syncthreads();
        float aH[4] = {0.f, 0.f, 0.f, 0.f}, aA[4] = {0.f, 0.f, 0.f, 0.f};
        #pragma unroll 8
        for (int kk = 0; kk < 16; ++kk) {
            int k = u16 * 16 + kk;
            float4 w4 = *(const float4*)&Ws[k * 128 + q5 * 4];
            float sh = sv[k], sa = sv[256 + k];
            aH[0] = fmaf(sh, w4.x, aH[0]); aA[0] = fmaf(sa, w4.x, aA[0]);
            aH[1] = fmaf(sh, w4.y, aH[1]); aA[1] = fmaf(sa, w4.y, aA[1]);
            aH[2] = fmaf(sh, w4.z, aH[2]); aA[2] = fmaf(sa, w4.z, aA[2]);
            aH[3] = fmaf(sh, w4.w, aH[3]); aA[3] = fmaf(sa, w4.w, aA[3]);
        }
        __syncthreads();
        *(float4*)&pR[u16 * 256 + q5 * 4]       = make_float4(aH[0], aH[1], aH[2], aH[3]);
        *(float4*)&pR[u16 * 256 + 128 + q5 * 4] = make_float4(aA[0], aA[1], aA[2], aA[3]);
        __syncthreads();
        if (t < 64) {
            int vec = t >> 5, fq = t & 31;
            float4 s = make_float4(0.f, 0.f, 0.f, 0.f);
            #pragma unroll
            for (int uu = 0; uu < 16; ++uu) {
                float4 p = *(const float4*)&pR[uu * 256 + vec * 128 + fq * 4];
                s.x += p.x; s.y += p.y; s.z += p.z; s.w += p.w;
            }
            float4 bb  = *(const float4*)&P.qb1[fq * 4];
            float4 w2q = *(const float4*)&P.qw2[fq * 4];
            float p = fmaxf(s.x + bb.x, 0.f) * w2q.x
                    + fmaxf(s.y + bb.y, 0.f) * w2q.y
                    + fmaxf(s.z + bb.z, 0.f) * w2q.z
                    + fmaxf(s.w + bb.w, 0.f) * w2q.w;
            #pragma unroll
            for (int o = 16; o > 0; o >>= 1) p += __shfl_down(p, o, 32);
            if ((t & 31) == 0) wsv[vec] = p;
        }
        __syncthreads();
        if (t == 0)
            P.outp[blk] = 0.5f + 0.5f * tanhf(wsv[0] - wsv[1]);
    }
}

// ---------------------------------------------------------------------------
extern "C" void kernel_launch(void* const* d_in, const int* in_sizes, int n_in,
                              void* d_out, int out_size, void* d_ws, size_t ws_size,
                              hipStream_t stream) {
    float* ws = (float*)d_ws;
    Params P;
    P.A    = (const float*)d_in[0];
    P.X    = (const float*)d_in[1];
    P.hm   = (const float*)d_in[2];
    P.e1w  = (const float*)d_in[3];
    P.e1b  = (const float*)d_in[4];
    P.e2w  = (const float*)d_in[5];
    P.e2b  = (const float*)d_in[6];
    P.rw0  = (const float*)d_in[7];
    P.rr0  = (const float*)d_in[8];
    P.rb0  = (const float*)d_in[9];
    P.law0 = (const float*)d_in[10];
    P.lab0 = (const float*)d_in[11];
    P.lbw0 = (const float*)d_in[12];
    P.lbb0 = (const float*)d_in[13];
    P.rw1  = (const float*)d_in[14];
    P.rr1  = (const float*)d_in[15];
    P.rb1  = (const float*)d_in[16];
    P.law1 = (const float*)d_in[17];
    P.lab1 = (const float*)d_in[18];
    P.lbw1 = (const float*)d_in[19];
    P.lbb1 = (const float*)d_in[20];
    P.ng   = (const float*)d_in[21];
    P.nbta = (const float*)d_in[22];
    P.pw1  = (const float*)d_in[23];
    P.pb1  = (const float*)d_in[24];
    P.pw2  = (const float*)d_in[25];
    P.pb2  = (const float*)d_in[26];
    P.qw1  = (const float*)d_in[27];
    P.qb1  = (const float*)d_in[28];
    P.qw2  = (const float*)d_in[29];
    P.qb2  = (const float*)d_in[30];
    P.H    = ws;                    // 262144
    P.H2   = ws + 262144;           // 262144
    P.hsum = ws + 524288;           // 2048
    P.asum = ws + 526336;           // 2048
    P.cnt  = (int*)(ws + 528384);   // 16 ints
    P.outp = (float*)d_out;

    k_init<<<17, 256, 0, stream>>>(P.hsum, P.cnt);
    k_mega<<<GRID, NT, 0, stream>>>(P);
}